// Round 4
// baseline (4195.974 us; speedup 1.0000x reference)
//
#include <hip/hip_runtime.h>
#include <math.h>

#define SLEN 512
#define BATCH 32
#define IDIM 768
#define HDIM 256
#define NDIM 1024  // 4*HDIM

typedef unsigned short u16;
typedef unsigned int u32;
typedef unsigned long long u64;
typedef __attribute__((ext_vector_type(8))) short short8;     // 8 bf16 (MFMA A/B frag)
typedef __attribute__((ext_vector_type(4))) float float4v;    // MFMA C/D frag
typedef __attribute__((ext_vector_type(4))) unsigned short ushort4v;
typedef __attribute__((ext_vector_type(4))) unsigned int uint4v;

__device__ __forceinline__ float bf2f(u16 v) {
    union { u32 u; float f; } c; c.u = ((u32)v) << 16; return c.f;
}
__device__ __forceinline__ u16 f2bf(float f) {
    union { float f; u32 u; } c; c.f = f;
    u32 u = c.u;
    return (u16)((u + 0x7fffu + ((u >> 16) & 1u)) >> 16);
}
__device__ __forceinline__ float sigm(float x) { return 1.f / (1.f + __expf(-x)); }
__device__ __forceinline__ float tanh_f(float x) { return 1.f - 2.f / (__expf(2.f * x) + 1.f); }

struct WPtrs {
    const float *Wi, *Ui, *bi, *Wf, *Uf, *bfp, *Wog, *Uog, *bog, *Wc, *Uc, *bc, *Wd, *bd;
};

// ---------------- kernel 0: weight conversion ----------------
__global__ void convert_kernel(WPtrs p, u16* __restrict__ W4t, u16* __restrict__ U4t,
                               float* __restrict__ b4) {
    const float* Wg[4] = {p.Wi, p.Wf, p.Wog, p.Wc};
    const float* Ug[4] = {p.Ui, p.Uf, p.Uog, p.Uc};
    const float* bg[4] = {p.bi, p.bfp, p.bog, p.bc};
    const int total = NDIM * IDIM + 5 * HDIM * HDIM + NDIM;
    for (int idx = blockIdx.x * blockDim.x + threadIdx.x; idx < total;
         idx += gridDim.x * blockDim.x) {
        int i = idx;
        if (i < NDIM * IDIM) {
            int n = i / IDIM, k = i - n * IDIM;
            W4t[i] = f2bf(Wg[n >> 8][k * HDIM + (n & 255)]);
        } else if ((i -= NDIM * IDIM) < 5 * HDIM * HDIM) {
            int g = i >> 16, rem = i & 65535, n = rem >> 8, k = rem & 255;
            const float* M = (g < 4) ? Ug[g] : p.Wd;
            U4t[i] = f2bf(M[k * HDIM + n]);
        } else {
            i -= 5 * HDIM * HDIM;
            b4[i] = bg[i >> 8][i & 255];
        }
    }
}

// ---------------- kernel 1: G = x @ W4 + b4  (bf16 MFMA, 128x128 tiles) ----------------
__global__ __launch_bounds__(256) void gemm_g_kernel(const float* __restrict__ x,
                                                     const u16* __restrict__ W4t,
                                                     const float* __restrict__ b4,
                                                     u16* __restrict__ G) {
    __shared__ u16 As[128][40];
    __shared__ u16 Bs[128][40];
    const int bn = blockIdx.x;   // 0..7
    const int bm = blockIdx.y;   // 0..127
    const int tid = threadIdx.x;
    const int w = tid >> 6, lane = tid & 63;
    const int wr = w >> 1, wc = w & 1;
    const int l15 = lane & 15, quad = lane >> 4;
    const int m0 = bm * 128, n0 = bn * 128;

    float4v acc[4][4];
#pragma unroll
    for (int a = 0; a < 4; ++a)
#pragma unroll
        for (int b = 0; b < 4; ++b) acc[a][b] = (float4v)(0.f);

    for (int kt = 0; kt < IDIM / 32; ++kt) {
        const int k0 = kt * 32;
#pragma unroll
        for (int i = 0; i < 4; ++i) {
            int idx = tid + 256 * i;
            int r = idx >> 3, seg = idx & 7;
            float4v xv = *(const float4v*)(x + (size_t)(m0 + r) * IDIM + k0 + seg * 4);
            ushort4v t;
            t.x = f2bf(xv.x); t.y = f2bf(xv.y); t.z = f2bf(xv.z); t.w = f2bf(xv.w);
            *(ushort4v*)(&As[r][seg * 4]) = t;
        }
#pragma unroll
        for (int i = 0; i < 2; ++i) {
            int idx = tid + 256 * i;
            int r = idx >> 2, seg = idx & 3;
            uint4v bv = *(const uint4v*)(W4t + (size_t)(n0 + r) * IDIM + k0 + seg * 8);
            *(uint4v*)(&Bs[r][seg * 8]) = bv;
        }
        __syncthreads();
        short8 afr[4], bfr[4];
#pragma unroll
        for (int mt = 0; mt < 4; ++mt) {
            int row = wr * 64 + mt * 16 + l15;
            afr[mt] = *(const short8*)(&As[row][quad * 8]);
        }
#pragma unroll
        for (int nt = 0; nt < 4; ++nt) {
            int col = wc * 64 + nt * 16 + l15;
            bfr[nt] = *(const short8*)(&Bs[col][quad * 8]);
        }
#pragma unroll
        for (int mt = 0; mt < 4; ++mt)
#pragma unroll
            for (int nt = 0; nt < 4; ++nt)
                acc[mt][nt] = __builtin_amdgcn_mfma_f32_16x16x32_bf16(afr[mt], bfr[nt],
                                                                      acc[mt][nt], 0, 0, 0);
        __syncthreads();
    }
#pragma unroll
    for (int mt = 0; mt < 4; ++mt)
#pragma unroll
        for (int nt = 0; nt < 4; ++nt) {
            int gm = m0 + wr * 64 + mt * 16 + quad * 4;
            int gn = n0 + wc * 64 + nt * 16 + l15;
            float bias = b4[gn];
#pragma unroll
            for (int r = 0; r < 4; ++r) {
                G[(size_t)(gm + r) * NDIM + gn] = f2bf(acc[mt][nt][r] + bias);
            }
        }
}

// ---------------- kernel 2: recurrence ----------------
// 4 blocks = 2 dirs x 2 halves(128 cols). 512 threads = 8 waves; wave w owns 16 cols
// (J = half*128 + w*16 + l15) of all 5 matrices, B-frags in VGPRs for all 512 steps.
// Peer half's h/c crosses via tagged u64 {tag|c|h} relaxed agent atomics; own half
// goes straight to parity-double-buffered LDS. One __syncthreads per step.
__global__ __launch_bounds__(512, 2) void recur_mfma_kernel(
    const float* __restrict__ times, const float* __restrict__ bd,
    const u16* __restrict__ U4t, const u16* __restrict__ G,
    u64* __restrict__ exch, float* __restrict__ out) {
    __shared__ u16 hL[2][32 * 264];  // [parity][b][k], row pad 264
    __shared__ u16 cL[2][32 * 264];
    const int d = blockIdx.x >> 1;
    const int hf = blockIdx.x & 1;
    const int tid = threadIdx.x;
    const int w = tid >> 6;
    const int lane = tid & 63;
    const int l15 = lane & 15;
    const int quad = lane >> 4;
    const int J = hf * 128 + w * 16 + l15;  // owned global hidden column
    const float bdec = bd[J];
    // exchange indexing: [(d,par,half)][b][colLocal]
    const int exbaseW = ((d << 2) | (hf ^ 0)) /*filled per-step*/, dummy = exbaseW;
    (void)dummy;
    // poll assignment: thread reads peer entries b=tid>>4, cols (tid&15)*8..+7
    const int pb = tid >> 4;
    const int pc = (tid & 15) << 3;

    // B fragments: B[k][n], lane n=l15, k = q*32 + quad*8 + e  -> U4t[mat][J][k]
    short8 Bf[5][8];
#pragma unroll
    for (int g = 0; g < 5; ++g)
#pragma unroll
        for (int q = 0; q < 8; ++q)
            Bf[g][q] = *(const short8*)(U4t + (g << 16) + (J << 8) + (q << 5) + (quad << 3));

    float creg[2][4], hreg[2][4];
#pragma unroll
    for (int mt = 0; mt < 2; ++mt)
#pragma unroll
        for (int r = 0; r < 4; ++r) { creg[mt][r] = 0.f; hreg[mt][r] = 0.f; }

    for (int s = 0; s < SLEN; ++s) {
        const int sf = d ? (SLEN - 1 - s) : s;              // G source row
        const int tt = d ? (s == 0 ? 0 : SLEN - s) : s;     // tb = [t0, t511..t1]

        // ---- prefetch (independent of exchange): G preacts -> acc init, T ----
        float4v acc[5][2];
#pragma unroll
        for (int g = 0; g < 4; ++g)
#pragma unroll
            for (int mt = 0; mt < 2; ++mt) {
                const u16* Gp = G + (size_t)((mt * 16 + quad * 4) * SLEN + sf) * NDIM + g * 256 + J;
                float4v a;
#pragma unroll
                for (int r = 0; r < 4; ++r) a[r] = bf2f(Gp[(size_t)r * SLEN * NDIM]);
                acc[g][mt] = a;
            }
        float Tv[2][4];
#pragma unroll
        for (int mt = 0; mt < 2; ++mt)
#pragma unroll
            for (int r = 0; r < 4; ++r) {
                const int b = mt * 16 + quad * 4 + r;
                Tv[mt][r] = 1.f / logf(times[b * SLEN + tt] + 2.718281828459045f);
            }
#pragma unroll
        for (int mt = 0; mt < 2; ++mt) acc[4][mt] = (float4v)(bdec);

        if (s > 0) {
            const int rp = (s - 1) & 1;  // parity holding h_{s-1}
            // ---- spin on peer's 128 cols: 8 contiguous u64 per thread (64B line) ----
            const u64* ex = exch + ((size_t)(((d << 1) | rp) * 2 + (1 - hf)) << 12) +
                            (pb << 7) + pc;
            u64 vals[8];
            bool ok = false;
            while (!ok) {
                ok = true;
#pragma unroll
                for (int i = 0; i < 8; ++i)
                    vals[i] = __hip_atomic_load(&ex[i], __ATOMIC_RELAXED,
                                                __HIP_MEMORY_SCOPE_AGENT);
#pragma unroll
                for (int i = 0; i < 8; ++i)
                    ok = ok && ((u32)vals[i] == (u32)(s - 1));
            }
            // stage peer half -> LDS parity rp
            short8 hv, cv;
#pragma unroll
            for (int i = 0; i < 8; ++i) {
                u32 hi = (u32)(vals[i] >> 32);
                hv[i] = (short)(u16)(hi & 0xffffu);
                cv[i] = (short)(u16)(hi >> 16);
            }
            const int doff = pb * 264 + (1 - hf) * 128 + pc;
            *(short8*)(&hL[rp][doff]) = hv;
            *(short8*)(&cL[rp][doff]) = cv;
            __syncthreads();  // stage + prev epilogue own-half writes visible

            // ---- A fragments from LDS: A[m][k], m=l15, k = q*32 + quad*8 + e ----
            short8 Ah[2][8], Ac[2][8];
#pragma unroll
            for (int mt = 0; mt < 2; ++mt)
#pragma unroll
                for (int q = 0; q < 8; ++q) {
                    const int off = (mt * 16 + l15) * 264 + q * 32 + quad * 8;
                    Ah[mt][q] = *(const short8*)(&hL[rp][off]);
                    Ac[mt][q] = *(const short8*)(&cL[rp][off]);
                }
#pragma unroll
            for (int q = 0; q < 8; ++q)
#pragma unroll
                for (int mt = 0; mt < 2; ++mt) {
                    acc[0][mt] = __builtin_amdgcn_mfma_f32_16x16x32_bf16(Ah[mt][q], Bf[0][q], acc[0][mt], 0, 0, 0);
                    acc[1][mt] = __builtin_amdgcn_mfma_f32_16x16x32_bf16(Ah[mt][q], Bf[1][q], acc[1][mt], 0, 0, 0);
                    acc[2][mt] = __builtin_amdgcn_mfma_f32_16x16x32_bf16(Ah[mt][q], Bf[2][q], acc[2][mt], 0, 0, 0);
                    acc[3][mt] = __builtin_amdgcn_mfma_f32_16x16x32_bf16(Ah[mt][q], Bf[3][q], acc[3][mt], 0, 0, 0);
                    acc[4][mt] = __builtin_amdgcn_mfma_f32_16x16x32_bf16(Ac[mt][q], Bf[4][q], acc[4][mt], 0, 0, 0);
                }
        }

        // ---- epilogue: C layout col=l15 (J), row=quad*4+r (batch) ----
        const int wp = s & 1;  // parity receiving h_s
        u64* exw = exch + ((size_t)(((d << 1) | wp) * 2 + hf) << 12);
#pragma unroll
        for (int mt = 0; mt < 2; ++mt)
#pragma unroll
            for (int r = 0; r < 4; ++r) {
                const int b = mt * 16 + quad * 4 + r;
                const float C_ST = tanh_f(acc[4][mt][r]);
                const float cs = creg[mt][r] - C_ST + Tv[mt][r] * C_ST;
                const float ig = sigm(acc[0][mt][r]);
                const float fg = sigm(acc[1][mt][r]);
                const float og = sigm(acc[2][mt][r]);
                const float Cc = sigm(acc[3][mt][r]);
                const float cn = fg * cs + ig * Cc;
                const float hn = og * tanh_f(cn);
                creg[mt][r] = cn;
                hreg[mt][r] = hn;
                const u16 hb16 = f2bf(hn), cb16 = f2bf(cn);
                const u32 payload = ((u32)cb16 << 16) | (u32)hb16;
                // remote: tagged entry for peer
                __hip_atomic_store(&exw[(b << 7) + (w * 16 + l15)],
                                   ((u64)payload << 32) | (u32)s, __ATOMIC_RELAXED,
                                   __HIP_MEMORY_SCOPE_AGENT);
                // local: own half straight into LDS parity wp
                hL[wp][b * 264 + J] = hb16;
                cL[wp][b * 264 + J] = cb16;
                out[((size_t)b * SLEN + s) * 512 + d * 256 + J] = hn;
            }
    }

    // h_last, c_last
    const size_t base2 = (size_t)BATCH * SLEN * 512;
#pragma unroll
    for (int mt = 0; mt < 2; ++mt)
#pragma unroll
        for (int r = 0; r < 4; ++r) {
            const int b = mt * 16 + quad * 4 + r;
            out[base2 + b * 512 + d * 256 + J] = hreg[mt][r];
            out[base2 + BATCH * 512 + b * 512 + d * 256 + J] = creg[mt][r];
        }
}

extern "C" void kernel_launch(void* const* d_in, const int* in_sizes, int n_in,
                              void* d_out, int out_size, void* d_ws, size_t ws_size,
                              hipStream_t stream) {
    const float* inputs = (const float*)d_in[0];
    const float* times = (const float*)d_in[1];
    WPtrs p;
    p.Wi = (const float*)d_in[2];  p.Ui = (const float*)d_in[3];  p.bi = (const float*)d_in[4];
    p.Wf = (const float*)d_in[5];  p.Uf = (const float*)d_in[6];  p.bfp = (const float*)d_in[7];
    p.Wog = (const float*)d_in[8]; p.Uog = (const float*)d_in[9]; p.bog = (const float*)d_in[10];
    p.Wc = (const float*)d_in[11]; p.Uc = (const float*)d_in[12]; p.bc = (const float*)d_in[13];
    p.Wd = (const float*)d_in[14]; p.bd = (const float*)d_in[15];

    char* ws = (char*)d_ws;
    u16* W4t = (u16*)ws;                   // 1024*768*2   = 1,572,864 B (gemm phase only)
    u16* U4t = (u16*)(ws + 1572864);       // 5*256*256*2  =   655,360 B
    float* b4 = (float*)(ws + 2228224);    // 1024*4       =     4,096 B
    u16* G = (u16*)(ws + 2232320);         // 16384*1024*2 = 33,554,432 B
    // recur-phase exchange aliases the (dead) W4t region:
    u64* exch = (u64*)ws;                  // [2d][2par][2half][32b][128c] u64 = 524,288 B

    hipLaunchKernelGGL(convert_kernel, dim3(1024), dim3(256), 0, stream, p, W4t, U4t, b4);
    hipLaunchKernelGGL(gemm_g_kernel, dim3(8, 128), dim3(256), 0, stream, inputs, W4t, b4, G);
    hipMemsetAsync(ws, 0xFF, 524288, stream);  // tags -> 0xFFFFFFFF (never a valid step)
    hipLaunchKernelGGL(recur_mfma_kernel, dim3(4), dim3(512), 0, stream, times, p.bd, U4t, G,
                       exch, (float*)d_out);
}